// Round 1
// baseline (693.698 us; speedup 1.0000x reference)
//
#include <hip/hip_runtime.h>
#include <hip/hip_bf16.h>

typedef float f32x4 __attribute__((ext_vector_type(4)));
typedef __bf16 bf16x8 __attribute__((ext_vector_type(8)));

#define BM 128
#define BN 128
#define BK 32
#define LDT 40   // padded LDS row stride in bf16 elements (80 B -> 2-way bank aliasing only)

// ---------------- abs-sum reduction (for per-tensor mean|w|) ----------------
__global__ __launch_bounds__(256) void abs_sum_kernel(const float* __restrict__ w, int n4,
                                                      double* __restrict__ out)
{
    double acc = 0.0;
    const float4* w4 = (const float4*)w;
    for (int i = blockIdx.x * blockDim.x + threadIdx.x; i < n4; i += gridDim.x * blockDim.x) {
        float4 v = w4[i];
        acc += (double)fabsf(v.x) + (double)fabsf(v.y) + (double)fabsf(v.z) + (double)fabsf(v.w);
    }
    for (int o = 32; o > 0; o >>= 1) acc += __shfl_down(acc, o, 64);
    __shared__ double part[4];
    int lane = threadIdx.x & 63, wv = threadIdx.x >> 6;
    if (lane == 0) part[wv] = acc;
    __syncthreads();
    if (threadIdx.x == 0) atomicAdd(out, part[0] + part[1] + part[2] + part[3]);
}

// ---------------- ternary weight quantization -> bf16 {-1,0,1} ----------------
__global__ __launch_bounds__(256) void wquant_kernel(const float* __restrict__ w, int n,
                                                     const double* __restrict__ sum, double inv_count,
                                                     __hip_bfloat16* __restrict__ out)
{
    float s = (float)(sum[0] * inv_count);
    s = fmaxf(s, 1e-5f);
    for (int i = blockIdx.x * blockDim.x + threadIdx.x; i < n; i += gridDim.x * blockDim.x) {
        float t = rintf(w[i] / s);           // rintf = round-half-even, matches jnp.round
        t = fminf(fmaxf(t, -1.0f), 1.0f);
        out[i] = __float2bfloat16(t);        // exact: {-1,0,1}
    }
}

// ---------------- FWHT over last dim + per-token absmax int8 quant ----------------
// One block per token. Butterfly pairing identical to the reference's iterative
// scheme (h = 1,2,4,...), so the fp32 adds are bit-exact vs numpy.
__global__ __launch_bounds__(256) void fwht_quant_kernel(
    const float* __restrict__ in, long in_stride,
    __hip_bfloat16* __restrict__ outq, long out_stride,
    float* __restrict__ scales, int n)
{
    extern __shared__ float sx[];
    __shared__ float red[4];
    __shared__ float gscale;
    const int tid = threadIdx.x;
    const long t = blockIdx.x;
    const float* row = in + t * in_stride;

    for (int e = tid; e < n; e += 256) sx[e] = row[e];
    __syncthreads();

    for (int h = 1; h < n; h <<= 1) {
        for (int p = tid; p < (n >> 1); p += 256) {
            int i = ((p & ~(h - 1)) << 1) | (p & (h - 1));
            float a = sx[i], b = sx[i + h];
            sx[i] = a + b;
            sx[i + h] = a - b;
        }
        __syncthreads();
    }

    const float rn = 1.0f / sqrtf((float)n);
    float m = 0.0f;
    for (int e = tid; e < n; e += 256) {
        float v = sx[e] * rn;
        sx[e] = v;
        m = fmaxf(m, fabsf(v));
    }
    for (int o = 32; o > 0; o >>= 1) m = fmaxf(m, __shfl_down(m, o, 64));
    int lane = tid & 63, wv = tid >> 6;
    if (lane == 0) red[wv] = m;
    __syncthreads();
    if (tid == 0) {
        float mm = fmaxf(fmaxf(red[0], red[1]), fmaxf(red[2], red[3]));
        mm = fmaxf(mm, 1e-5f);
        float sc = 127.0f / mm;
        gscale = sc;
        scales[t] = sc;
    }
    __syncthreads();
    const float sc = gscale;
    __hip_bfloat16* orow = outq + t * out_stride;
    for (int e = tid; e < n; e += 256) {
        float q = rintf(sx[e] * sc);
        q = fminf(fmaxf(q, -127.0f), 127.0f);
        orow[e] = __float2bfloat16(q);       // small integer: exact in bf16
    }
}

// ---------------- bf16 MFMA GEMM, C[t][o] = sum_k A[t][k]*B[o][k], fused epilogue ----
// 128x128x32 tiles, 4 waves, each wave does a 64x64 region as 4x4 MFMA 16x16x32 tiles.
__global__ __launch_bounds__(256) void gemm_bt_kernel(
    const __hip_bfloat16* __restrict__ A, int lda,
    const __hip_bfloat16* __restrict__ B, int ldb,
    float* __restrict__ C, int ldc,
    int K,
    const float* __restrict__ sx,
    const double* __restrict__ wsum, double inv_count,
    int do_relu2)
{
    __shared__ __align__(16) __hip_bfloat16 As[BM * LDT];
    __shared__ __align__(16) __hip_bfloat16 Bs[BN * LDT];

    const int tid = threadIdx.x;
    const int row0 = blockIdx.y * BM;
    const int col0 = blockIdx.x * BN;
    const int lane = tid & 63;
    const int wave = tid >> 6;
    const int wm = (wave >> 1) * 64;
    const int wn = (wave & 1) * 64;

    f32x4 acc[4][4] = {};

    // staging: thread T covers row T/4 (+64), 16-byte segment T%4
    const int srow = tid >> 2;
    const int scol = (tid & 3) * 8;
    const __hip_bfloat16* Ag = A + (size_t)(row0 + srow) * lda + scol;
    const __hip_bfloat16* Bg = B + (size_t)(col0 + srow) * ldb + scol;
    const size_t ldA64 = (size_t)64 * lda, ldB64 = (size_t)64 * ldb;

    const int fr = lane & 15;          // MFMA m/n within tile
    const int fk = (lane >> 4) * 8;    // MFMA k chunk

    for (int k0 = 0; k0 < K; k0 += BK) {
        int4 a0 = *(const int4*)(Ag + k0);
        int4 a1 = *(const int4*)(Ag + k0 + ldA64);
        int4 b0 = *(const int4*)(Bg + k0);
        int4 b1 = *(const int4*)(Bg + k0 + ldB64);
        __syncthreads();
        *(int4*)(As + srow * LDT + scol) = a0;
        *(int4*)(As + (srow + 64) * LDT + scol) = a1;
        *(int4*)(Bs + srow * LDT + scol) = b0;
        *(int4*)(Bs + (srow + 64) * LDT + scol) = b1;
        __syncthreads();

        bf16x8 af[4], bfr[4];
        #pragma unroll
        for (int i = 0; i < 4; i++) {
            af[i]  = *(const bf16x8*)(As + (wm + i * 16 + fr) * LDT + fk);
            bfr[i] = *(const bf16x8*)(Bs + (wn + i * 16 + fr) * LDT + fk);
        }
        #pragma unroll
        for (int i = 0; i < 4; i++)
            #pragma unroll
            for (int j = 0; j < 4; j++)
                acc[i][j] = __builtin_amdgcn_mfma_f32_16x16x32_bf16(af[i], bfr[j], acc[i][j], 0, 0, 0);
    }

    // epilogue: out = acc * s_w / scale_x[row]; optional relu^2
    float sw = (float)(wsum[0] * inv_count);
    sw = fmaxf(sw, 1e-5f);
    const int qd = lane >> 4;
    #pragma unroll
    for (int i = 0; i < 4; i++) {
        #pragma unroll
        for (int r = 0; r < 4; r++) {
            int rowm = row0 + wm + i * 16 + qd * 4 + r;   // D row = (lane>>4)*4 + reg
            float esc = sw / sx[rowm];
            float* crow = C + (size_t)rowm * ldc + col0 + wn;
            #pragma unroll
            for (int j = 0; j < 4; j++) {
                float v = acc[i][j][r] * esc;             // D col = lane&15
                if (do_relu2) { v = fmaxf(v, 0.0f); v = v * v; }
                crow[j * 16 + fr] = v;
            }
        }
    }
}

extern "C" void kernel_launch(void* const* d_in, const int* in_sizes, int n_in,
                              void* d_out, int out_size, void* d_ws, size_t ws_size,
                              hipStream_t stream)
{
    const float* X   = (const float*)d_in[0];   // (4,2048,2048) f32
    const float* Wup = (const float*)d_in[1];   // (4096,2048)   f32
    const float* Wdn = (const float*)d_in[2];   // (2048,4096)   f32
    float* out = (float*)d_out;                 // (4,2048,2048) f32

    const int Mtok = 8192, H = 2048, I = 4096;
    const int NW = H * I;                       // 8388608 = 2^23 weights per tensor

    // workspace layout
    char* ws = (char*)d_ws;
    double* sums = (double*)ws;                                  // 2 doubles
    float* sx1 = (float*)(ws + 1024);                            // 8192 f32
    float* sx2 = (float*)(ws + 1024 + 32768);                    // 8192 f32
    __hip_bfloat16* wqup = (__hip_bfloat16*)(ws + (1 << 20));    // 16 MB
    __hip_bfloat16* wqdn = wqup + (size_t)NW;                    // 16 MB
    __hip_bfloat16* xq1  = wqdn + (size_t)NW;                    // 32 MB
    float* hbuf = (float*)(xq1 + (size_t)Mtok * H);              // 128 MB (h f32; xq2 bf16 overlaid per-row)

    hipMemsetAsync(sums, 0, 16, stream);
    abs_sum_kernel<<<512, 256, 0, stream>>>(Wup, NW / 4, &sums[0]);
    abs_sum_kernel<<<512, 256, 0, stream>>>(Wdn, NW / 4, &sums[1]);
    const double invc = 1.0 / (double)NW;       // exactly 2^-23
    wquant_kernel<<<2048, 256, 0, stream>>>(Wup, NW, &sums[0], invc, wqup);
    wquant_kernel<<<2048, 256, 0, stream>>>(Wdn, NW, &sums[1], invc, wqdn);

    // stage 1: FWHT(H) + quant
    fwht_quant_kernel<<<Mtok, 256, H * 4, stream>>>(X, H, xq1, H, sx1, H);
    // GEMM1 + relu^2 fused -> hbuf (f32, ld=I)
    gemm_bt_kernel<<<dim3(I / BN, Mtok / BM), 256, 0, stream>>>(
        xq1, H, wqup, H, hbuf, I, H, sx1, &sums[0], invc, 1);
    // stage 2: FWHT(I) + quant; xq2 (bf16) overlaid on hbuf rows (row stride 2*I bf16 = 16 KB)
    fwht_quant_kernel<<<Mtok, 256, I * 4, stream>>>(hbuf, I, (__hip_bfloat16*)hbuf, 2 * I, sx2, I);
    // GEMM2 -> out
    gemm_bt_kernel<<<dim3(H / BN, Mtok / BM), 256, 0, stream>>>(
        (const __hip_bfloat16*)hbuf, 2 * I, wqdn, I, out, H, I, sx2, &sums[1], invc, 0);
}

// Round 2
// 625.234 us; speedup vs baseline: 1.1095x; 1.1095x over previous
//
#include <hip/hip_runtime.h>
#include <hip/hip_bf16.h>

typedef float f32x4 __attribute__((ext_vector_type(4)));
typedef __bf16 bf16x8 __attribute__((ext_vector_type(8)));

#define BM 128
#define BN 128
#define BK 32

// async global->LDS, 16B per lane; LDS dest = uniform base + lane*16
#define GLL16(g, l) __builtin_amdgcn_global_load_lds( \
    (const __attribute__((address_space(1))) void*)(g), \
    (__attribute__((address_space(3))) void*)(l), 16, 0, 0)

// ---------------- abs-sum reduction (for per-tensor mean|w|) ----------------
__global__ __launch_bounds__(256) void abs_sum_kernel(const float* __restrict__ w, int n4,
                                                      double* __restrict__ out)
{
    double acc = 0.0;
    const float4* w4 = (const float4*)w;
    for (int i = blockIdx.x * blockDim.x + threadIdx.x; i < n4; i += gridDim.x * blockDim.x) {
        float4 v = w4[i];
        acc += (double)fabsf(v.x) + (double)fabsf(v.y) + (double)fabsf(v.z) + (double)fabsf(v.w);
    }
    for (int o = 32; o > 0; o >>= 1) acc += __shfl_down(acc, o, 64);
    __shared__ double part[4];
    int lane = threadIdx.x & 63, wv = threadIdx.x >> 6;
    if (lane == 0) part[wv] = acc;
    __syncthreads();
    if (threadIdx.x == 0) atomicAdd(out, part[0] + part[1] + part[2] + part[3]);
}

// ---------------- ternary weight quantization -> bf16 {-1,0,1} ----------------
__global__ __launch_bounds__(256) void wquant_kernel(const float* __restrict__ w, int n,
                                                     const double* __restrict__ sum, double inv_count,
                                                     __hip_bfloat16* __restrict__ out)
{
    float s = (float)(sum[0] * inv_count);
    s = fmaxf(s, 1e-5f);
    for (int i = blockIdx.x * blockDim.x + threadIdx.x; i < n; i += gridDim.x * blockDim.x) {
        float t = rintf(w[i] / s);           // rintf = round-half-even, matches jnp.round
        t = fminf(fmaxf(t, -1.0f), 1.0f);
        out[i] = __float2bfloat16(t);        // exact: {-1,0,1}
    }
}

// ---------------- in-register H_16 butterfly helper ----------------
// Applies butterfly stages h=1..2^(NS-1) over the 16-element array; for NS<4
// this is independent 2^NS transforms on each aligned subgroup.
template<int NS>
__device__ __forceinline__ void hreg(float* v)
{
    #pragma unroll
    for (int h = 1; h < (1 << NS); h <<= 1)
        #pragma unroll
        for (int i = 0; i < 16; i++)
            if ((i & h) == 0) { float a = v[i], b = v[i + h]; v[i] = a + b; v[i + h] = a - b; }
}

// ---------------- FWHT + per-token absmax int8 quant (3-phase register FWHT) ----
// N = token length, TOKS tokens per 256-thread block. L = 256/TOKS threads/token,
// each thread holds 16 elements. Stages applied in ascending h order -> bit-exact
// vs the reference's iterative scheme:
//   P1 : h=1,2,4,8      thread holds 16 consecutive elems
//   P3': h=16..128(/64) thread holds idx = o + 256*s + 16*j   (j=0..15)
//   P2': h=256..N/2     thread holds idx = o + 16*s + L*j
template<int N, int TOKS>
__global__ __launch_bounds__(256) void fwht_quant_kernel(
    const float* __restrict__ in, long in_stride,
    __hip_bfloat16* __restrict__ outq, long out_stride,
    float* __restrict__ scales)
{
    constexpr int L = 256 / TOKS;          // threads per token (128 or 256)
    static_assert(N == 16 * L, "N must be 16*threads-per-token");
    __shared__ float sx[TOKS * N];
    __shared__ float red[4];

    const int tid = threadIdx.x;
    const int tk  = tid / L;
    const int lt  = tid % L;
    const long tok = (long)blockIdx.x * TOKS + tk;
    const float* row = in + tok * in_stride;
    float* s = sx + tk * N;

    float v[16];
    {   // vectorized load of 16 consecutive floats
        const float4* r4 = (const float4*)(row + (size_t)lt * 16);
        float4 a[4];
        #pragma unroll
        for (int i = 0; i < 4; i++) a[i] = r4[i];
        #pragma unroll
        for (int i = 0; i < 4; i++) {
            v[4*i] = a[i].x; v[4*i+1] = a[i].y; v[4*i+2] = a[i].z; v[4*i+3] = a[i].w;
        }
    }
    hreg<4>(v);                            // h = 1,2,4,8
    #pragma unroll
    for (int i = 0; i < 4; i++)
        *(float4*)(s + lt * 16 + 4 * i) = make_float4(v[4*i], v[4*i+1], v[4*i+2], v[4*i+3]);
    __syncthreads();

    const int o = lt & 15, ss = lt >> 4;
    #pragma unroll
    for (int j = 0; j < 16; j++) v[j] = s[o + 256 * ss + 16 * j];
    hreg<(L == 256) ? 4 : 3>(v);           // h = 16..128 (L=256) or 16..64 (L=128)
    #pragma unroll
    for (int j = 0; j < 16; j++) s[o + 256 * ss + 16 * j] = v[j];
    __syncthreads();

    #pragma unroll
    for (int j = 0; j < 16; j++) v[j] = s[o + 16 * ss + L * j];
    hreg<4>(v);                            // top 4 stages, h = N/16 .. N/2

    // normalize + absmax
    const float rn = 1.0f / sqrtf((float)N);
    float m = 0.0f;
    #pragma unroll
    for (int j = 0; j < 16; j++) { v[j] *= rn; m = fmaxf(m, fabsf(v[j])); }
    for (int off = 32; off > 0; off >>= 1) m = fmaxf(m, __shfl_down(m, off, 64));
    if ((tid & 63) == 0) red[tid >> 6] = m;
    __syncthreads();
    float mm;
    if (TOKS == 1) mm = fmaxf(fmaxf(red[0], red[1]), fmaxf(red[2], red[3]));
    else           mm = fmaxf(red[2 * tk], red[2 * tk + 1]);
    mm = fmaxf(mm, 1e-5f);
    const float sc = 127.0f / mm;
    if (lt == 0) scales[tok] = sc;

    // quantize from registers, repack through LDS (reused as ushort) for vector stores
    ushort* ut = (ushort*)sx + tk * N;
    #pragma unroll
    for (int j = 0; j < 16; j++) {
        float q = fminf(fmaxf(rintf(v[j] * sc), -127.0f), 127.0f);
        __hip_bfloat16 qb = __float2bfloat16(q);     // small integer: exact in bf16
        ut[o + 16 * ss + L * j] = *(ushort*)&qb;
    }
    __syncthreads();
    __hip_bfloat16* orow = outq + tok * out_stride;
    const int4* src = (const int4*)ut;
    int4* dst = (int4*)orow;
    dst[2 * lt]     = src[2 * lt];
    dst[2 * lt + 1] = src[2 * lt + 1];
}

// ---------------- bf16 MFMA GEMM, C[t][o] = sum_k A[t][k]*B[o][k], fused epilogue ----
// 128x128x32 tiles, 4 waves, global_load_lds width-16 staging (m97 structure).
// LDS layout is unpadded row-major [row][32]: required by global_load_lds's
// uniform-base + lane*16 dest mapping (lane l -> row l>>2, 16B seg l&3).
__global__ __launch_bounds__(256) void gemm_bt_kernel(
    const __hip_bfloat16* __restrict__ A, int lda,
    const __hip_bfloat16* __restrict__ B, int ldb,
    float* __restrict__ C, int ldc,
    int K,
    const float* __restrict__ sx,
    const double* __restrict__ wsum, double inv_count,
    int do_relu2)
{
    __shared__ __align__(16) __hip_bfloat16 As[BM * BK];
    __shared__ __align__(16) __hip_bfloat16 Bs[BN * BK];

    const int tid = threadIdx.x;
    const int row0 = blockIdx.y * BM;
    const int col0 = blockIdx.x * BN;
    const int lane = tid & 63;
    const int wave = tid >> 6;
    const int wm = (wave >> 1) * 64;
    const int wn = (wave & 1) * 64;

    f32x4 acc[4][4] = {};

    // staging: wave w covers rows [w*16, w*16+16) and +64; lane l -> row w*16+(l>>2), seg l&3
    const int srow = wave * 16 + (lane >> 2);
    const int scol = (lane & 3) * 8;
    const __hip_bfloat16* Ag = A + (size_t)(row0 + srow) * lda + scol;
    const __hip_bfloat16* Bg = B + (size_t)(col0 + srow) * ldb + scol;
    const size_t ldA64 = (size_t)64 * lda, ldB64 = (size_t)64 * ldb;
    __hip_bfloat16* As0 = As + (wave * 16) * BK;         // wave-uniform LDS bases
    __hip_bfloat16* As1 = As + (wave * 16 + 64) * BK;
    __hip_bfloat16* Bs0 = Bs + (wave * 16) * BK;
    __hip_bfloat16* Bs1 = Bs + (wave * 16 + 64) * BK;

    const int fr = lane & 15;          // MFMA m/n within tile
    const int fk = (lane >> 4) * 8;    // MFMA k chunk

    for (int k0 = 0; k0 < K; k0 += BK) {
        __syncthreads();               // previous tile fully consumed
        GLL16(Ag + k0,         As0);
        GLL16(Ag + k0 + ldA64, As1);
        GLL16(Bg + k0,         Bs0);
        GLL16(Bg + k0 + ldB64, Bs1);
        __syncthreads();               // drains vmcnt -> tile ready

        bf16x8 af[4], bfr[4];
        #pragma unroll
        for (int i = 0; i < 4; i++) {
            af[i]  = *(const bf16x8*)(As + (wm + i * 16 + fr) * BK + fk);
            bfr[i] = *(const bf16x8*)(Bs + (wn + i * 16 + fr) * BK + fk);
        }
        #pragma unroll
        for (int i = 0; i < 4; i++)
            #pragma unroll
            for (int j = 0; j < 4; j++)
                acc[i][j] = __builtin_amdgcn_mfma_f32_16x16x32_bf16(af[i], bfr[j], acc[i][j], 0, 0, 0);
    }

    // epilogue: out = acc * s_w / scale_x[row]; optional relu^2
    float sw = (float)(wsum[0] * inv_count);
    sw = fmaxf(sw, 1e-5f);
    const int qd = lane >> 4;
    #pragma unroll
    for (int i = 0; i < 4; i++) {
        #pragma unroll
        for (int r = 0; r < 4; r++) {
            int rowm = row0 + wm + i * 16 + qd * 4 + r;   // D row = (lane>>4)*4 + reg
            float esc = sw / sx[rowm];
            float* crow = C + (size_t)rowm * ldc + col0 + wn;
            #pragma unroll
            for (int j = 0; j < 4; j++) {
                float v = acc[i][j][r] * esc;             // D col = lane&15
                if (do_relu2) { v = fmaxf(v, 0.0f); v = v * v; }
                crow[j * 16 + fr] = v;
            }
        }
    }
}

extern "C" void kernel_launch(void* const* d_in, const int* in_sizes, int n_in,
                              void* d_out, int out_size, void* d_ws, size_t ws_size,
                              hipStream_t stream)
{
    const float* X   = (const float*)d_in[0];   // (4,2048,2048) f32
    const float* Wup = (const float*)d_in[1];   // (4096,2048)   f32
    const float* Wdn = (const float*)d_in[2];   // (2048,4096)   f32
    float* out = (float*)d_out;                 // (4,2048,2048) f32

    const int Mtok = 8192, H = 2048, I = 4096;
    const int NW = H * I;                       // 8388608 = 2^23 weights per tensor

    // workspace layout
    char* ws = (char*)d_ws;
    double* sums = (double*)ws;                                  // 2 doubles
    float* sx1 = (float*)(ws + 1024);                            // 8192 f32
    float* sx2 = (float*)(ws + 1024 + 32768);                    // 8192 f32
    __hip_bfloat16* wqup = (__hip_bfloat16*)(ws + (1 << 20));    // 16 MB
    __hip_bfloat16* wqdn = wqup + (size_t)NW;                    // 16 MB
    __hip_bfloat16* xq1  = wqdn + (size_t)NW;                    // 32 MB
    float* hbuf = (float*)(xq1 + (size_t)Mtok * H);              // 128 MB (h f32; xq2 bf16 overlaid per-row)

    hipMemsetAsync(sums, 0, 16, stream);
    abs_sum_kernel<<<512, 256, 0, stream>>>(Wup, NW / 4, &sums[0]);
    abs_sum_kernel<<<512, 256, 0, stream>>>(Wdn, NW / 4, &sums[1]);
    const double invc = 1.0 / (double)NW;       // exactly 2^-23
    wquant_kernel<<<2048, 256, 0, stream>>>(Wup, NW, &sums[0], invc, wqup);
    wquant_kernel<<<2048, 256, 0, stream>>>(Wdn, NW, &sums[1], invc, wqdn);

    // stage 1: FWHT(H=2048) + quant, 2 tokens/block
    fwht_quant_kernel<2048, 2><<<Mtok / 2, 256, 0, stream>>>(X, H, xq1, H, sx1);
    // GEMM1 + relu^2 fused -> hbuf (f32, ld=I)
    gemm_bt_kernel<<<dim3(I / BN, Mtok / BM), 256, 0, stream>>>(
        xq1, H, wqup, H, hbuf, I, H, sx1, &sums[0], invc, 1);
    // stage 2: FWHT(I=4096) + quant; xq2 (bf16) overlaid on hbuf rows (row stride 2*I bf16 = 16 KB)
    fwht_quant_kernel<4096, 1><<<Mtok, 256, 0, stream>>>(hbuf, I, (__hip_bfloat16*)hbuf, 2 * I, sx2);
    // GEMM2 -> out
    gemm_bt_kernel<<<dim3(H / BN, Mtok / BM), 256, 0, stream>>>(
        (const __hip_bfloat16*)hbuf, 2 * I, wqdn, I, out, H, I, sx2, &sums[1], invc, 0);
}

// Round 3
// 584.664 us; speedup vs baseline: 1.1865x; 1.0694x over previous
//
#include <hip/hip_runtime.h>
#include <hip/hip_bf16.h>

typedef float f32x4 __attribute__((ext_vector_type(4)));
typedef __bf16 bf16x8 __attribute__((ext_vector_type(8)));

#define BM 128
#define BN 128
#define BK 32   // per sub-tile; 2 sub-tiles staged per barrier (effective K-step 64)

// async global->LDS, 16B per lane; LDS dest = uniform base + lane*16
#define GLL16(g, l) __builtin_amdgcn_global_load_lds( \
    (const __attribute__((address_space(1))) void*)(g), \
    (__attribute__((address_space(3))) void*)(l), 16, 0, 0)

// ---------------- abs-sum reduction (for per-tensor mean|w|) ----------------
__global__ __launch_bounds__(256) void abs_sum_kernel(const float* __restrict__ w, int n4,
                                                      double* __restrict__ out)
{
    double acc = 0.0;
    const float4* w4 = (const float4*)w;
    for (int i = blockIdx.x * blockDim.x + threadIdx.x; i < n4; i += gridDim.x * blockDim.x) {
        float4 v = w4[i];
        acc += (double)fabsf(v.x) + (double)fabsf(v.y) + (double)fabsf(v.z) + (double)fabsf(v.w);
    }
    for (int o = 32; o > 0; o >>= 1) acc += __shfl_down(acc, o, 64);
    __shared__ double part[4];
    int lane = threadIdx.x & 63, wv = threadIdx.x >> 6;
    if (lane == 0) part[wv] = acc;
    __syncthreads();
    if (threadIdx.x == 0) atomicAdd(out, part[0] + part[1] + part[2] + part[3]);
}

// ---------------- ternary weight quantization -> bf16 {-1,0,1} ----------------
__global__ __launch_bounds__(256) void wquant_kernel(const float* __restrict__ w, int n,
                                                     const double* __restrict__ sum, double inv_count,
                                                     __hip_bfloat16* __restrict__ out)
{
    float s = (float)(sum[0] * inv_count);
    s = fmaxf(s, 1e-5f);
    for (int i = blockIdx.x * blockDim.x + threadIdx.x; i < n; i += gridDim.x * blockDim.x) {
        float t = rintf(w[i] / s);           // rintf = round-half-even, matches jnp.round
        t = fminf(fmaxf(t, -1.0f), 1.0f);
        out[i] = __float2bfloat16(t);        // exact: {-1,0,1}
    }
}

// ---------------- in-register H_16 butterfly helper ----------------
template<int NS>
__device__ __forceinline__ void hreg(float* v)
{
    #pragma unroll
    for (int h = 1; h < (1 << NS); h <<= 1)
        #pragma unroll
        for (int i = 0; i < 16; i++)
            if ((i & h) == 0) { float a = v[i], b = v[i + h]; v[i] = a + b; v[i + h] = a - b; }
}

// ---------------- FWHT + per-token absmax int8 quant (3-phase register FWHT) ----
// Stages applied in ascending h order -> bit-exact vs the reference scheme.
template<int N, int TOKS>
__global__ __launch_bounds__(256) void fwht_quant_kernel(
    const float* __restrict__ in, long in_stride,
    __hip_bfloat16* __restrict__ outq, long out_stride,
    float* __restrict__ scales)
{
    constexpr int L = 256 / TOKS;          // threads per token (128 or 256)
    static_assert(N == 16 * L, "N must be 16*threads-per-token");
    __shared__ float sx[TOKS * N];
    __shared__ float red[4];

    const int tid = threadIdx.x;
    const int tk  = tid / L;
    const int lt  = tid % L;
    const long tok = (long)blockIdx.x * TOKS + tk;
    const float* row = in + tok * in_stride;
    float* s = sx + tk * N;

    float v[16];
    {
        const float4* r4 = (const float4*)(row + (size_t)lt * 16);
        float4 a[4];
        #pragma unroll
        for (int i = 0; i < 4; i++) a[i] = r4[i];
        #pragma unroll
        for (int i = 0; i < 4; i++) {
            v[4*i] = a[i].x; v[4*i+1] = a[i].y; v[4*i+2] = a[i].z; v[4*i+3] = a[i].w;
        }
    }
    hreg<4>(v);                            // h = 1,2,4,8
    #pragma unroll
    for (int i = 0; i < 4; i++)
        *(float4*)(s + lt * 16 + 4 * i) = make_float4(v[4*i], v[4*i+1], v[4*i+2], v[4*i+3]);
    __syncthreads();

    const int o = lt & 15, ss = lt >> 4;
    #pragma unroll
    for (int j = 0; j < 16; j++) v[j] = s[o + 256 * ss + 16 * j];
    hreg<(L == 256) ? 4 : 3>(v);           // h = 16..128 (L=256) or 16..64 (L=128)
    #pragma unroll
    for (int j = 0; j < 16; j++) s[o + 256 * ss + 16 * j] = v[j];
    __syncthreads();

    #pragma unroll
    for (int j = 0; j < 16; j++) v[j] = s[o + 16 * ss + L * j];
    hreg<4>(v);                            // top 4 stages

    const float rn = 1.0f / sqrtf((float)N);
    float m = 0.0f;
    #pragma unroll
    for (int j = 0; j < 16; j++) { v[j] *= rn; m = fmaxf(m, fabsf(v[j])); }
    for (int off = 32; off > 0; off >>= 1) m = fmaxf(m, __shfl_down(m, off, 64));
    if ((tid & 63) == 0) red[tid >> 6] = m;
    __syncthreads();
    float mm;
    if (TOKS == 1) mm = fmaxf(fmaxf(red[0], red[1]), fmaxf(red[2], red[3]));
    else           mm = fmaxf(red[2 * tk], red[2 * tk + 1]);
    mm = fmaxf(mm, 1e-5f);
    const float sc = 127.0f / mm;
    if (lt == 0) scales[tok] = sc;

    ushort* ut = (ushort*)sx + tk * N;
    #pragma unroll
    for (int j = 0; j < 16; j++) {
        float q = fminf(fmaxf(rintf(v[j] * sc), -127.0f), 127.0f);
        __hip_bfloat16 qb = __float2bfloat16(q);     // small integer: exact in bf16
        ut[o + 16 * ss + L * j] = *(ushort*)&qb;
    }
    __syncthreads();
    __hip_bfloat16* orow = outq + tok * out_stride;
    const int4* src = (const int4*)ut;
    int4* dst = (int4*)orow;
    dst[2 * lt]     = src[2 * lt];
    dst[2 * lt + 1] = src[2 * lt + 1];
}

// ---------------- bf16 MFMA GEMM, C[t][o] = sum_k A[t][k]*B[o][k], fused epilogue ----
// 128x128 tiles, 4 waves. Two 32-wide k sub-tiles staged per barrier (8x GLL16),
// 32 MFMAs per drain. 1-D grid with XCD row-band swizzle: xcd = bid&7 owns a
// contiguous y-band, x innermost -> each A row-band fetched by exactly one XCD.
__global__ __launch_bounds__(256) void gemm_bt_kernel(
    const __hip_bfloat16* __restrict__ A, int lda,
    const __hip_bfloat16* __restrict__ B, int ldb,
    float* __restrict__ C, int ldc,
    int K, int lognx,
    const float* __restrict__ sx,
    const double* __restrict__ wsum, double inv_count,
    int do_relu2)
{
    __shared__ __align__(16) __hip_bfloat16 As[2][BM * BK];
    __shared__ __align__(16) __hip_bfloat16 Bs[2][BN * BK];

    // XCD row-band swizzle
    const int bid = blockIdx.x;
    const int xcd = bid & 7;
    const int n = bid >> 3;
    const int nper = gridDim.x >> 3;             // blocks per XCD
    const int bx = n & ((1 << lognx) - 1);
    const int by = xcd * (nper >> lognx) + (n >> lognx);
    const int row0 = by * BM;
    const int col0 = bx * BN;

    const int tid = threadIdx.x;
    const int lane = tid & 63;
    const int wave = tid >> 6;
    const int wm = (wave >> 1) * 64;
    const int wn = (wave & 1) * 64;

    f32x4 acc[4][4] = {};

    // staging: wave w covers rows [w*16, w*16+16) and +64; lane l -> row w*16+(l>>2), seg l&3
    const int srow = wave * 16 + (lane >> 2);
    const int scol = (lane & 3) * 8;
    const __hip_bfloat16* Ag = A + (size_t)(row0 + srow) * lda + scol;
    const __hip_bfloat16* Bg = B + (size_t)(col0 + srow) * ldb + scol;
    const size_t ldA64 = (size_t)64 * lda, ldB64 = (size_t)64 * ldb;
    const int wb0 = (wave * 16) * BK;            // wave-uniform LDS offsets
    const int wb1 = (wave * 16 + 64) * BK;

    const int fr = lane & 15;          // MFMA m/n within tile
    const int fk = (lane >> 4) * 8;    // MFMA k chunk

    for (int k0 = 0; k0 < K; k0 += 2 * BK) {
        __syncthreads();               // previous double-tile fully consumed
        GLL16(Ag + k0,              &As[0][wb0]);
        GLL16(Ag + k0 + ldA64,      &As[0][wb1]);
        GLL16(Bg + k0,              &Bs[0][wb0]);
        GLL16(Bg + k0 + ldB64,      &Bs[0][wb1]);
        GLL16(Ag + k0 + BK,         &As[1][wb0]);
        GLL16(Ag + k0 + BK + ldA64, &As[1][wb1]);
        GLL16(Bg + k0 + BK,         &Bs[1][wb0]);
        GLL16(Bg + k0 + BK + ldB64, &Bs[1][wb1]);
        __syncthreads();               // drains vmcnt -> both sub-tiles ready

        #pragma unroll
        for (int p = 0; p < 2; p++) {
            bf16x8 af[4], bfr[4];
            #pragma unroll
            for (int i = 0; i < 4; i++) {
                af[i]  = *(const bf16x8*)(&As[p][(wm + i * 16 + fr) * BK + fk]);
                bfr[i] = *(const bf16x8*)(&Bs[p][(wn + i * 16 + fr) * BK + fk]);
            }
            #pragma unroll
            for (int i = 0; i < 4; i++)
                #pragma unroll
                for (int j = 0; j < 4; j++)
                    acc[i][j] = __builtin_amdgcn_mfma_f32_16x16x32_bf16(af[i], bfr[j], acc[i][j], 0, 0, 0);
        }
    }

    // epilogue: out = acc * s_w / scale_x[row]; optional relu^2
    float sw = (float)(wsum[0] * inv_count);
    sw = fmaxf(sw, 1e-5f);
    const int qd = lane >> 4;
    #pragma unroll
    for (int i = 0; i < 4; i++) {
        #pragma unroll
        for (int r = 0; r < 4; r++) {
            int rowm = row0 + wm + i * 16 + qd * 4 + r;   // D row = (lane>>4)*4 + reg
            float esc = sw / sx[rowm];
            float* crow = C + (size_t)rowm * ldc + col0 + wn;
            #pragma unroll
            for (int j = 0; j < 4; j++) {
                float v = acc[i][j][r] * esc;             // D col = lane&15
                if (do_relu2) { v = fmaxf(v, 0.0f); v = v * v; }
                crow[j * 16 + fr] = v;
            }
        }
    }
}

extern "C" void kernel_launch(void* const* d_in, const int* in_sizes, int n_in,
                              void* d_out, int out_size, void* d_ws, size_t ws_size,
                              hipStream_t stream)
{
    const float* X   = (const float*)d_in[0];   // (4,2048,2048) f32
    const float* Wup = (const float*)d_in[1];   // (4096,2048)   f32
    const float* Wdn = (const float*)d_in[2];   // (2048,4096)   f32
    float* out = (float*)d_out;                 // (4,2048,2048) f32

    const int Mtok = 8192, H = 2048, I = 4096;
    const int NW = H * I;                       // 8388608 = 2^23 weights per tensor

    // workspace layout
    char* ws = (char*)d_ws;
    double* sums = (double*)ws;                                  // 2 doubles
    float* sx1 = (float*)(ws + 1024);                            // 8192 f32
    float* sx2 = (float*)(ws + 1024 + 32768);                    // 8192 f32
    __hip_bfloat16* wqup = (__hip_bfloat16*)(ws + (1 << 20));    // 16 MB
    __hip_bfloat16* wqdn = wqup + (size_t)NW;                    // 16 MB
    __hip_bfloat16* xq1  = wqdn + (size_t)NW;                    // 32 MB
    float* hbuf = (float*)(xq1 + (size_t)Mtok * H);              // 128 MB (h f32; xq2 bf16 overlaid per-row)

    hipMemsetAsync(sums, 0, 16, stream);
    abs_sum_kernel<<<512, 256, 0, stream>>>(Wup, NW / 4, &sums[0]);
    abs_sum_kernel<<<512, 256, 0, stream>>>(Wdn, NW / 4, &sums[1]);
    const double invc = 1.0 / (double)NW;       // exactly 2^-23
    wquant_kernel<<<2048, 256, 0, stream>>>(Wup, NW, &sums[0], invc, wqup);
    wquant_kernel<<<2048, 256, 0, stream>>>(Wdn, NW, &sums[1], invc, wqdn);

    // stage 1: FWHT(H=2048) + quant, 2 tokens/block
    fwht_quant_kernel<2048, 2><<<Mtok / 2, 256, 0, stream>>>(X, H, xq1, H, sx1);
    // GEMM1 + relu^2 fused -> hbuf (f32, ld=I); grid 32x64 -> 1-D swizzled, lognx=5
    gemm_bt_kernel<<<(I / BN) * (Mtok / BM), 256, 0, stream>>>(
        xq1, H, wqup, H, hbuf, I, H, 5, sx1, &sums[0], invc, 1);
    // stage 2: FWHT(I=4096) + quant; xq2 (bf16) overlaid on hbuf rows (row stride 2*I bf16 = 16 KB)
    fwht_quant_kernel<4096, 1><<<Mtok, 256, 0, stream>>>(hbuf, I, (__hip_bfloat16*)hbuf, 2 * I, sx2);
    // GEMM2 -> out; grid 16x64 -> 1-D swizzled, lognx=4
    gemm_bt_kernel<<<(H / BN) * (Mtok / BM), 256, 0, stream>>>(
        (const __hip_bfloat16*)hbuf, 2 * I, wqdn, I, out, H, I, 4, sx2, &sums[1], invc, 0);
}

// Round 4
// 406.315 us; speedup vs baseline: 1.7073x; 1.4389x over previous
//
#include <hip/hip_runtime.h>
#include <hip/hip_bf16.h>

typedef int i32x4 __attribute__((ext_vector_type(4)));

#define BM 128
#define BN 128
#define BK 64   // i8 bytes per k sub-tile; 2 sub-tiles staged per barrier (K-step 128)

// async global->LDS, 16B per lane; LDS dest = uniform base + lane*16
#define GLL16(g, l) __builtin_amdgcn_global_load_lds( \
    (const __attribute__((address_space(1))) void*)(g), \
    (__attribute__((address_space(3))) void*)(l), 16, 0, 0)

// ---------------- abs-sum reduction (for per-tensor mean|w|) ----------------
__global__ __launch_bounds__(256) void abs_sum_kernel(const float* __restrict__ w, int n4,
                                                      double* __restrict__ out)
{
    double acc = 0.0;
    const float4* w4 = (const float4*)w;
    for (int i = blockIdx.x * blockDim.x + threadIdx.x; i < n4; i += gridDim.x * blockDim.x) {
        float4 v = w4[i];
        acc += (double)fabsf(v.x) + (double)fabsf(v.y) + (double)fabsf(v.z) + (double)fabsf(v.w);
    }
    for (int o = 32; o > 0; o >>= 1) acc += __shfl_down(acc, o, 64);
    __shared__ double part[4];
    int lane = threadIdx.x & 63, wv = threadIdx.x >> 6;
    if (lane == 0) part[wv] = acc;
    __syncthreads();
    if (threadIdx.x == 0) atomicAdd(out, part[0] + part[1] + part[2] + part[3]);
}

// ---------------- ternary weight quantization -> i8 {-1,0,1} ----------------
__global__ __launch_bounds__(256) void wquant_kernel(const float* __restrict__ w, int n4,
                                                     const double* __restrict__ sum, double inv_count,
                                                     char* __restrict__ out)
{
    float s = (float)(sum[0] * inv_count);
    s = fmaxf(s, 1e-5f);
    const float4* w4 = (const float4*)w;
    char4* o4 = (char4*)out;
    for (int i = blockIdx.x * blockDim.x + threadIdx.x; i < n4; i += gridDim.x * blockDim.x) {
        float4 v = w4[i];
        char4 c;
        c.x = (char)fminf(fmaxf(rintf(v.x / s), -1.0f), 1.0f);   // rintf = round-half-even
        c.y = (char)fminf(fmaxf(rintf(v.y / s), -1.0f), 1.0f);
        c.z = (char)fminf(fmaxf(rintf(v.z / s), -1.0f), 1.0f);
        c.w = (char)fminf(fmaxf(rintf(v.w / s), -1.0f), 1.0f);
        o4[i] = c;
    }
}

// ---------------- in-register H_16 butterfly helper ----------------
template<int NS>
__device__ __forceinline__ void hreg(float* v)
{
    #pragma unroll
    for (int h = 1; h < (1 << NS); h <<= 1)
        #pragma unroll
        for (int i = 0; i < 16; i++)
            if ((i & h) == 0) { float a = v[i], b = v[i + h]; v[i] = a + b; v[i + h] = a - b; }
}

// ---------------- FWHT + per-token absmax int8 quant (3-phase register FWHT) ----
// Stages applied in ascending h order -> bit-exact vs the reference scheme.
// Output: int8 row (exact integers in [-127,127]).
template<int N, int TOKS>
__global__ __launch_bounds__(256) void fwht_quant_kernel(
    const float* __restrict__ in, long in_stride,
    char* __restrict__ outq, long out_stride,
    float* __restrict__ scales)
{
    constexpr int L = 256 / TOKS;          // threads per token (128 or 256)
    static_assert(N == 16 * L, "N must be 16*threads-per-token");
    __shared__ float sx[TOKS * N];
    __shared__ float red[4];

    const int tid = threadIdx.x;
    const int tk  = tid / L;
    const int lt  = tid % L;
    const long tok = (long)blockIdx.x * TOKS + tk;
    const float* row = in + tok * in_stride;
    float* s = sx + tk * N;

    float v[16];
    {
        const float4* r4 = (const float4*)(row + (size_t)lt * 16);
        float4 a[4];
        #pragma unroll
        for (int i = 0; i < 4; i++) a[i] = r4[i];
        #pragma unroll
        for (int i = 0; i < 4; i++) {
            v[4*i] = a[i].x; v[4*i+1] = a[i].y; v[4*i+2] = a[i].z; v[4*i+3] = a[i].w;
        }
    }
    hreg<4>(v);                            // h = 1,2,4,8
    #pragma unroll
    for (int i = 0; i < 4; i++)
        *(float4*)(s + lt * 16 + 4 * i) = make_float4(v[4*i], v[4*i+1], v[4*i+2], v[4*i+3]);
    __syncthreads();

    const int o = lt & 15, ss = lt >> 4;
    #pragma unroll
    for (int j = 0; j < 16; j++) v[j] = s[o + 256 * ss + 16 * j];
    hreg<(L == 256) ? 4 : 3>(v);           // h = 16..128 (L=256) or 16..64 (L=128)
    #pragma unroll
    for (int j = 0; j < 16; j++) s[o + 256 * ss + 16 * j] = v[j];
    __syncthreads();

    #pragma unroll
    for (int j = 0; j < 16; j++) v[j] = s[o + 16 * ss + L * j];
    hreg<4>(v);                            // top 4 stages

    const float rn = 1.0f / sqrtf((float)N);
    float m = 0.0f;
    #pragma unroll
    for (int j = 0; j < 16; j++) { v[j] *= rn; m = fmaxf(m, fabsf(v[j])); }
    for (int off = 32; off > 0; off >>= 1) m = fmaxf(m, __shfl_down(m, off, 64));
    if ((tid & 63) == 0) red[tid >> 6] = m;
    __syncthreads();
    float mm;
    if (TOKS == 1) mm = fmaxf(fmaxf(red[0], red[1]), fmaxf(red[2], red[3]));
    else           mm = fmaxf(red[2 * tk], red[2 * tk + 1]);
    mm = fmaxf(mm, 1e-5f);
    const float sc = 127.0f / mm;
    if (lt == 0) scales[tok] = sc;
    __syncthreads();                       // sx about to be reused as i8 buffer

    // quantize from registers, repack through LDS (as i8) for 16B vector stores
    char* ct = (char*)sx + tk * N;
    #pragma unroll
    for (int j = 0; j < 16; j++) {
        float q = fminf(fmaxf(rintf(v[j] * sc), -127.0f), 127.0f);
        ct[o + 16 * ss + L * j] = (char)q;
    }
    __syncthreads();
    int4* dst = (int4*)(outq + tok * out_stride);
    dst[lt] = ((const int4*)ct)[lt];       // N/16 int4s per row == L threads
}

// ---------------- i8 MFMA GEMM, C[t][o] = sum_k A[t][k]*B[o][k], fused epilogue ----
// 128x128 tiles, 4 waves, mfma_i32_16x16x64_i8 (exact integer accumulation).
// Two 64-byte k sub-tiles staged per barrier (8x GLL16), 32 MFMAs per drain.
// 1-D grid with XCD row-band swizzle (xcd = bid&7 owns a contiguous y-band).
__global__ __launch_bounds__(256) void gemm_bt_kernel(
    const char* __restrict__ A, int lda,
    const char* __restrict__ B, int ldb,
    float* __restrict__ C, int ldc,
    int K, int lognx,
    const float* __restrict__ sx,
    const double* __restrict__ wsum, double inv_count,
    int do_relu2)
{
    __shared__ __align__(16) char As[2][BM * BK];   // 8 KB each
    __shared__ __align__(16) char Bs[2][BN * BK];

    // XCD row-band swizzle
    const int bid = blockIdx.x;
    const int xcd = bid & 7;
    const int n = bid >> 3;
    const int nper = gridDim.x >> 3;             // blocks per XCD
    const int bx = n & ((1 << lognx) - 1);
    const int by = xcd * (nper >> lognx) + (n >> lognx);
    const int row0 = by * BM;
    const int col0 = bx * BN;

    const int tid = threadIdx.x;
    const int lane = tid & 63;
    const int wave = tid >> 6;
    const int wm = (wave >> 1) * 64;
    const int wn = (wave & 1) * 64;

    i32x4 acc[4][4] = {};

    // staging: wave w covers rows w*16+[0,16) and +64; lane l -> row +(l>>2), 16B seg l&3
    const int srow = wave * 16 + (lane >> 2);
    const int scol = (lane & 3) * 16;
    const char* Ag = A + (size_t)(row0 + srow) * lda + scol;
    const char* Bg = B + (size_t)(col0 + srow) * ldb + scol;
    const size_t ldA64 = (size_t)64 * lda, ldB64 = (size_t)64 * ldb;
    const int wb0 = (wave * 16) * BK;            // wave-uniform LDS offsets
    const int wb1 = (wave * 16 + 64) * BK;

    const int fr = lane & 15;          // MFMA m/n within tile
    const int fk = (lane >> 4) * 16;   // MFMA k chunk (16 i8 = 16 B)

    for (int k0 = 0; k0 < K; k0 += 2 * BK) {
        __syncthreads();               // previous double-tile fully consumed
        GLL16(Ag + k0,              &As[0][wb0]);
        GLL16(Ag + k0 + ldA64,      &As[0][wb1]);
        GLL16(Bg + k0,              &Bs[0][wb0]);
        GLL16(Bg + k0 + ldB64,      &Bs[0][wb1]);
        GLL16(Ag + k0 + BK,         &As[1][wb0]);
        GLL16(Ag + k0 + BK + ldA64, &As[1][wb1]);
        GLL16(Bg + k0 + BK,         &Bs[1][wb0]);
        GLL16(Bg + k0 + BK + ldB64, &Bs[1][wb1]);
        __syncthreads();               // drains vmcnt -> both sub-tiles ready

        #pragma unroll
        for (int p = 0; p < 2; p++) {
            i32x4 af[4], bfr[4];
            #pragma unroll
            for (int i = 0; i < 4; i++) {
                af[i]  = *(const i32x4*)(&As[p][(wm + i * 16 + fr) * BK + fk]);
                bfr[i] = *(const i32x4*)(&Bs[p][(wn + i * 16 + fr) * BK + fk]);
            }
            #pragma unroll
            for (int i = 0; i < 4; i++)
                #pragma unroll
                for (int j = 0; j < 4; j++)
                    acc[i][j] = __builtin_amdgcn_mfma_i32_16x16x64_i8(af[i], bfr[j], acc[i][j], 0, 0, 0);
        }
    }

    // epilogue: out = (float)acc * s_w / scale_x[row]; optional relu^2
    float sw = (float)(wsum[0] * inv_count);
    sw = fmaxf(sw, 1e-5f);
    const int qd = lane >> 4;
    #pragma unroll
    for (int i = 0; i < 4; i++) {
        #pragma unroll
        for (int r = 0; r < 4; r++) {
            int rowm = row0 + wm + i * 16 + qd * 4 + r;   // D row = (lane>>4)*4 + reg
            float esc = sw / sx[rowm];
            float* crow = C + (size_t)rowm * ldc + col0 + wn;
            #pragma unroll
            for (int j = 0; j < 4; j++) {
                float v = (float)acc[i][j][r] * esc;      // D col = lane&15
                if (do_relu2) { v = fmaxf(v, 0.0f); v = v * v; }
                crow[j * 16 + fr] = v;
            }
        }
    }
}

extern "C" void kernel_launch(void* const* d_in, const int* in_sizes, int n_in,
                              void* d_out, int out_size, void* d_ws, size_t ws_size,
                              hipStream_t stream)
{
    const float* X   = (const float*)d_in[0];   // (4,2048,2048) f32
    const float* Wup = (const float*)d_in[1];   // (4096,2048)   f32
    const float* Wdn = (const float*)d_in[2];   // (2048,4096)   f32
    float* out = (float*)d_out;                 // (4,2048,2048) f32

    const int Mtok = 8192, H = 2048, I = 4096;
    const int NW = H * I;                       // 8388608 = 2^23 weights per tensor

    // workspace layout
    char* ws = (char*)d_ws;
    double* sums = (double*)ws;                                  // 2 doubles
    float* sx1 = (float*)(ws + 1024);                            // 8192 f32
    float* sx2 = (float*)(ws + 1024 + 32768);                    // 8192 f32
    char* wqup = ws + (1 << 20);                                 // 8.4 MB (i8)
    char* wqdn = wqup + (size_t)NW;                              // 8.4 MB
    char* xq1  = wqdn + (size_t)NW;                              // 16.8 MB (i8)
    float* hbuf = (float*)(xq1 + (size_t)Mtok * H);              // 134 MB (h f32; xq2 i8 overlaid per-row)

    hipMemsetAsync(sums, 0, 16, stream);
    abs_sum_kernel<<<512, 256, 0, stream>>>(Wup, NW / 4, &sums[0]);
    abs_sum_kernel<<<512, 256, 0, stream>>>(Wdn, NW / 4, &sums[1]);
    const double invc = 1.0 / (double)NW;       // exactly 2^-23
    wquant_kernel<<<1024, 256, 0, stream>>>(Wup, NW / 4, &sums[0], invc, wqup);
    wquant_kernel<<<1024, 256, 0, stream>>>(Wdn, NW / 4, &sums[1], invc, wqdn);

    // stage 1: FWHT(H=2048) + quant, 2 tokens/block
    fwht_quant_kernel<2048, 2><<<Mtok / 2, 256, 0, stream>>>(X, H, xq1, H, sx1);
    // GEMM1 + relu^2 fused -> hbuf (f32, ld=I); grid 32x64 -> 1-D swizzled, lognx=5
    gemm_bt_kernel<<<(I / BN) * (Mtok / BM), 256, 0, stream>>>(
        xq1, H, wqup, H, hbuf, I, H, 5, sx1, &sums[0], invc, 1);
    // stage 2: FWHT(I=4096) + quant; xq2 (i8) overlaid on hbuf rows (stride 4*I bytes)
    fwht_quant_kernel<4096, 1><<<Mtok, 256, 0, stream>>>(hbuf, I, (char*)hbuf, 4 * I, sx2);
    // GEMM2 -> out; grid 16x64 -> 1-D swizzled, lognx=4
    gemm_bt_kernel<<<(H / BN) * (Mtok / BM), 256, 0, stream>>>(
        (const char*)hbuf, 4 * I, wqdn, I, out, H, I, 4, sx2, &sums[1], invc, 0);
}